// Round 14
// baseline (62.413 us; speedup 1.0000x reference)
//
#include <hip/hip_runtime.h>
#include <hip/hip_bf16.h>

// Problem constants
#define B_ROWS 4096
#define NN     8192
#define DD     128
#define NSPLIT 32           // column splits (= #cs blocks); merged across wn in LDS
#define TSTEPS 4            // 128 pair-cols per block / 32 per t-step
#define CSHIFT 128.0f       // fixed logsumexp shift (log2 domain)

typedef __attribute__((ext_vector_type(8))) short s8v;   // 8 bf16 (4 VGPR)
typedef __attribute__((ext_vector_type(4))) float f4v;   // 4 f32
typedef __attribute__((ext_vector_type(2))) float f2v;
typedef unsigned int u32;

static constexpr float SCALE_H = 1.6986436f;      // sqrt(2*log2(e)); folds /TEMP and log2e into the matmul
static constexpr float SCALE2  = 2.8853900818f;   // 2*log2(e)
static constexpr float LN2     = 0.6931471805599453f;

__device__ __forceinline__ float fast_exp2(float x) {
#if __has_builtin(__builtin_amdgcn_exp2f)
    return __builtin_amdgcn_exp2f(x);      // bare v_exp_f32
#else
    return exp2f(x);
#endif
}

typedef __attribute__((address_space(1))) const u32 gu32;
typedef __attribute__((address_space(3))) u32 lu32;
__device__ __forceinline__ void gload_lds16(const void* g, void* l) {
    // async global->LDS, 16B/lane; dest = lds base + lane*16 (wave-uniform base)
    __builtin_amdgcn_global_load_lds((gu32*)g, (lu32*)l, 16, 0, 0);
}

// ---- kernel 1: fused bf16-prep + pos dot ----
__global__ void hpos_kernel(const float* __restrict__ hi, const float* __restrict__ hj,
                            __hip_bfloat16* __restrict__ hb, float* __restrict__ pos2) {
    int w = threadIdx.x >> 6, l = threadIdx.x & 63;
    int row = blockIdx.x * 4 + w;
    f2v a = ((const f2v*)(hi + (size_t)row * DD))[l];
    f2v b = ((const f2v*)(hj + (size_t)row * DD))[l];
    float d = a[0] * b[0] + a[1] * b[1];
    #pragma unroll
    for (int off = 32; off; off >>= 1) d += __shfl_xor(d, off, 64);
    if (l == 0) pos2[row] = SCALE2 * d;
    union { ushort2 u2; __hip_bfloat16 h[2]; } ua, ub;
    ua.h[0] = __float2bfloat16(a[0] * SCALE_H);
    ua.h[1] = __float2bfloat16(a[1] * SCALE_H);
    ub.h[0] = __float2bfloat16(b[0] * SCALE_H);
    ub.h[1] = __float2bfloat16(b[1] * SCALE_H);
    ((ushort2*)(hb + (size_t)row * DD))[l] = ua.u2;
    ((ushort2*)(hb + (size_t)(row + B_ROWS) * DD))[l] = ub.u2;
}

// ---- kernel 2: fused sim*S2 + masked fixed-shift sum-of-exp2 ----
// R12 skeleton (proven stable): 512-thr / 8-wave blocks (wm 0..3, wn 0..1),
// 64 pair-rows x 128 pair-cols, grid 2048 = 64 rb x 32 cs. B tiles dbuf via
// global_load_lds (linear dest, pre-swizzled source); plain __syncthreads
// 2-phase schedule.
// R13 delta: S panel moved from LDS to 16 per-thread f32 regs (s2r[4][4],
// mask folded). LDS -> 32 KB -> 4 blocks/CU (2048 thr, 100% occupancy cap).
__global__ __launch_bounds__(512, 4)
void main_kernel(const __hip_bfloat16* __restrict__ hb, const float* __restrict__ S,
                 float* __restrict__ ssplit) {
    __shared__ short ldsB[2][64][128];            // 2 x 16 KB B tiles (swizzled)

    const int tid = threadIdx.x;
    const int l  = tid & 63;
    const int w  = tid >> 6;             // 0..7
    const int wm = w >> 1, wn = w & 1;
    const int rb = blockIdx.x & 63;
    const int cs = blockIdx.x >> 6;
    const int r0 = rb * 64 + wm * 16;    // wave pair-row base
    const int c0 = cs * 128;             // block pair-col base
    const int lc = l & 15;               // frag row/col within 16
    const int lk = l >> 4;               // k-group

    const s8v* hb8 = (const s8v*)hb;     // 16 x s8v per row of 128 bf16

#define STAGE(BUF, T) do {                                                        \
    _Pragma("unroll")                                                             \
    for (int i = 0; i < 2; i++) {                                                 \
        const int seg  = w * 2 + i;        /* 0..15 */                            \
        const int lrw  = seg * 4 + lk;     /* local row 0..63 */                  \
        const int grow = c0 + (T) * 32 + ((lrw < 32) ? lrw : (lrw - 32 + B_ROWS));\
        const int sc16 = lc ^ (lrw & 7);   /* source pre-swizzle */               \
        gload_lds16((const char*)hb + ((size_t)grow << 8) + (sc16 << 4),          \
                    (char*)&ldsB[BUF][seg * 4][0]);                               \
    }                                                                             \
} while (0)

    // prologue: stage B tile 0 (async); load per-thread S values; load A frags
    STAGE(0, 0);

    // s2r[r][t] = (col==row) ? 0 : 1 - S^2  for this thread's 4 rows x 4 t-cols
    float s2r[4][4];
    {
        const int grow0 = rb * 64 + wm * 16 + lk * 4;   // + r
        const int gcol0 = c0 + wn * 16 + lc;            // + t*32
        const float* gS = S + (size_t)grow0 * B_ROWS + gcol0;
        #pragma unroll
        for (int r = 0; r < 4; r++)
            #pragma unroll
            for (int t = 0; t < 4; t++) {
                float x = gS[(size_t)r * B_ROWS + t * 32];
                bool msk = (gcol0 + t * 32) == (grow0 + r);
                s2r[r][t] = msk ? 0.f : fmaf(-x, x, 1.f);
            }
    }

    s8v afr[2][4];
    #pragma unroll
    for (int fm = 0; fm < 2; fm++) {
        int ar = r0 + lc + fm * B_ROWS;
        #pragma unroll
        for (int kk = 0; kk < 4; kk++)
            afr[fm][kk] = hb8[ar * 16 + kk * 4 + lk];
    }
    __syncthreads();   // B tile 0 + afr ready

    float ssum[2][4];
    #pragma unroll
    for (int fm = 0; fm < 2; fm++)
        #pragma unroll
        for (int r = 0; r < 4; r++) ssum[fm][r] = 0.f;

    // loop-invariant ds_read addrs; +BUF*16384 / +8192 are immediate offsets
    const char* bp[4];
    {
        const char* bb = (const char*)ldsB + (wn * 16 + lc) * 256;
        #pragma unroll
        for (int kk = 0; kk < 4; kk++)
            bp[kk] = bb + (((kk * 4 + lk) ^ (lc & 7)) << 4);
    }

#define COMPUTE(BUF, T) do {                                                      \
    f4v acc[2][2];                                                                \
    _Pragma("unroll")                                                             \
    for (int fm = 0; fm < 2; fm++)                                                \
        _Pragma("unroll")                                                         \
        for (int fh = 0; fh < 2; fh++) acc[fm][fh] = f4v{0.f, 0.f, 0.f, 0.f};     \
    _Pragma("unroll")                                                             \
    for (int kk = 0; kk < 4; kk++) {                                              \
        s8v bf0 = *(const s8v*)(bp[kk] + ((BUF) * 16384));                        \
        s8v bf1 = *(const s8v*)(bp[kk] + ((BUF) * 16384 + 8192));                 \
        _Pragma("unroll")                                                         \
        for (int fm = 0; fm < 2; fm++) {                                          \
            acc[fm][0] = __builtin_amdgcn_mfma_f32_16x16x32_bf16(                 \
                afr[fm][kk], bf0, acc[fm][0], 0, 0, 0);                           \
            acc[fm][1] = __builtin_amdgcn_mfma_f32_16x16x32_bf16(                 \
                afr[fm][kk], bf1, acc[fm][1], 0, 0, 0);                           \
        }                                                                         \
    }                                                                             \
    _Pragma("unroll")                                                             \
    for (int r = 0; r < 4; r++) {                                                 \
        const float s2 = s2r[r][(T)];                                             \
        _Pragma("unroll")                                                         \
        for (int fm = 0; fm < 2; fm++) {                                          \
            float e0 = fast_exp2(fmaf(acc[fm][0][r], s2, -CSHIFT));               \
            float e1 = fast_exp2(fmaf(acc[fm][1][r], s2, -CSHIFT));               \
            ssum[fm][r] += e0 + e1;                                               \
        }                                                                         \
    }                                                                             \
} while (0)

    // 2-phase pipeline: stage next tile, compute current, barrier
    STAGE(1, 1); COMPUTE(0, 0); __syncthreads();
    STAGE(0, 2); COMPUTE(1, 1); __syncthreads();
    STAGE(1, 3); COMPUTE(0, 2); __syncthreads();
                 COMPUTE(1, 3);

#undef STAGE
#undef COMPUTE

    // pure-sum reduce over the 16 lanes holding each row, merge wn via LDS
    // merge scratch aliased into ldsB[0] (dead after COMPUTE(0,2) + barrier;
    // COMPUTE(1,3) reads only ldsB[1])
    float* sexb = (float*)&ldsB[0][0][0];   // [wn][fm][rho] = 256 floats
    #pragma unroll
    for (int fm = 0; fm < 2; fm++) {
        #pragma unroll
        for (int r = 0; r < 4; r++) {
            float ss = ssum[fm][r];
            #pragma unroll
            for (int off = 1; off < 16; off <<= 1)
                ss += __shfl_xor(ss, off, 64);
            if (lc == 0) {
                int rho = wm * 16 + lk * 4 + r;   // block-local pair-row 0..63
                sexb[wn * 128 + fm * 64 + rho] = ss;
            }
        }
    }
    __syncthreads();
    if (tid < 128) {
        int fm = tid >> 6, rho = tid & 63;
        float ss = sexb[fm * 64 + rho] + sexb[128 + fm * 64 + rho];
        int gr = rb * 64 + rho + fm * B_ROWS;
        ssplit[cs * NN + gr] = ss;
    }
}

// ---- kernel 3a: per-row split sum + lse, block partial sums (parallel) ----
__global__ __launch_bounds__(256)
void reduce_kernel(const float* __restrict__ ssplit, const float* __restrict__ pos2,
                   float* __restrict__ partial) {
    __shared__ float red[256];
    const int n = blockIdx.x * 256 + threadIdx.x;   // n < 8192
    float p = pos2[n & (B_ROWS - 1)];
    float Ssum = fast_exp2(p - CSHIFT);             // pos logit seeds the sum
    #pragma unroll
    for (int sp = 0; sp < NSPLIT; sp++)
        Ssum += ssplit[sp * NN + n];
    red[threadIdx.x] = (CSHIFT + log2f(Ssum)) - p;  // log2 units
    __syncthreads();
    for (int st = 128; st; st >>= 1) {
        if (threadIdx.x < st) red[threadIdx.x] += red[threadIdx.x + st];
        __syncthreads();
    }
    if (threadIdx.x == 0) partial[blockIdx.x] = red[0];
}

// ---- kernel 3b: deterministic final sum over 32 partials ----
__global__ void final_kernel(const float* __restrict__ partial, float* __restrict__ out) {
    if (threadIdx.x == 0) {
        float s = 0.f;
        #pragma unroll
        for (int i = 0; i < 32; i++) s += partial[i];
        out[0] = s * (LN2 / (float)NN);
    }
}

extern "C" void kernel_launch(void* const* d_in, const int* in_sizes, int n_in,
                              void* d_out, int out_size, void* d_ws, size_t ws_size,
                              hipStream_t stream) {
    (void)in_sizes; (void)n_in; (void)out_size; (void)ws_size;
    const float* hi = (const float*)d_in[0];
    const float* hj = (const float*)d_in[1];
    const float* S  = (const float*)d_in[2];

    char* ws = (char*)d_ws;
    __hip_bfloat16* hb = (__hip_bfloat16*)ws;                        // 2 MB
    float* pos2   = (float*)(ws + 2097152);                          // 16 KB
    float* ssplit = (float*)(ws + 2097152 + 16384);                  // 1 MB (32 splits)
    float* partial= (float*)(ws + 2097152 + 16384 + 1048576);        // 128 B

    hpos_kernel<<<1024, 256, 0, stream>>>(hi, hj, hb, pos2);
    main_kernel<<<2048, 512, 0, stream>>>(hb, S, ssplit);
    reduce_kernel<<<32, 256, 0, stream>>>(ssplit, pos2, partial);
    final_kernel<<<1, 64, 0, stream>>>(partial, (float*)d_out);
}

// Round 15
// 62.250 us; speedup vs baseline: 1.0026x; 1.0026x over previous
//
#include <hip/hip_runtime.h>
#include <hip/hip_bf16.h>

// Problem constants
#define B_ROWS 4096
#define NN     8192
#define DD     128
#define NSPLIT 32           // column splits (= #cs blocks); merged across wn in LDS
#define TSTEPS 4            // 128 pair-cols per block / 32 per t-step
#define CSHIFT 128.0f       // fixed logsumexp shift (log2 domain)

typedef __attribute__((ext_vector_type(8))) short s8v;   // 8 bf16 (4 VGPR)
typedef __attribute__((ext_vector_type(4))) float f4v;   // 4 f32
typedef __attribute__((ext_vector_type(2))) float f2v;
typedef unsigned int u32;

static constexpr float SCALE_H = 1.6986436f;      // sqrt(2*log2(e)); folds /TEMP and log2e into the matmul
static constexpr float SCALE2  = 2.8853900818f;   // 2*log2(e)
static constexpr float LN2     = 0.6931471805599453f;

__device__ __forceinline__ float fast_exp2(float x) {
#if __has_builtin(__builtin_amdgcn_exp2f)
    return __builtin_amdgcn_exp2f(x);      // bare v_exp_f32
#else
    return exp2f(x);
#endif
}

typedef __attribute__((address_space(1))) const u32 gu32;
typedef __attribute__((address_space(3))) u32 lu32;
__device__ __forceinline__ void gload_lds16(const void* g, void* l) {
    // async global->LDS, 16B/lane; dest = lds base + lane*16 (wave-uniform base)
    __builtin_amdgcn_global_load_lds((gu32*)g, (lu32*)l, 16, 0, 0);
}

// ---- kernel 1: fused bf16-prep + pos dot ----
__global__ void hpos_kernel(const float* __restrict__ hi, const float* __restrict__ hj,
                            __hip_bfloat16* __restrict__ hb, float* __restrict__ pos2) {
    int w = threadIdx.x >> 6, l = threadIdx.x & 63;
    int row = blockIdx.x * 4 + w;
    f2v a = ((const f2v*)(hi + (size_t)row * DD))[l];
    f2v b = ((const f2v*)(hj + (size_t)row * DD))[l];
    float d = a[0] * b[0] + a[1] * b[1];
    #pragma unroll
    for (int off = 32; off; off >>= 1) d += __shfl_xor(d, off, 64);
    if (l == 0) pos2[row] = SCALE2 * d;
    union { ushort2 u2; __hip_bfloat16 h[2]; } ua, ub;
    ua.h[0] = __float2bfloat16(a[0] * SCALE_H);
    ua.h[1] = __float2bfloat16(a[1] * SCALE_H);
    ub.h[0] = __float2bfloat16(b[0] * SCALE_H);
    ub.h[1] = __float2bfloat16(b[1] * SCALE_H);
    ((ushort2*)(hb + (size_t)row * DD))[l] = ua.u2;
    ((ushort2*)(hb + (size_t)(row + B_ROWS) * DD))[l] = ub.u2;
}

// ---- kernel 2: fused sim*S2 + masked fixed-shift sum-of-exp2 ----
// R13 structure: 512-thr / 8-wave blocks (wm 0..3, wn 0..1), 64 pair-rows x
// 128 pair-cols, grid 2048 = 64 rb x 32 cs; B tiles dbuf via global_load_lds;
// plain __syncthreads 2-phase schedule; S in 16 per-thread f32 regs.
// R14 delta: keep-alive asm pins the s2r loads in the PROLOGUE (R13's
// regression = compiler sank them into the loop; VGPR 64 proved it).
__global__ __launch_bounds__(512, 4)
void main_kernel(const __hip_bfloat16* __restrict__ hb, const float* __restrict__ S,
                 float* __restrict__ ssplit) {
    __shared__ short ldsB[2][64][128];            // 2 x 16 KB B tiles (swizzled)

    const int tid = threadIdx.x;
    const int l  = tid & 63;
    const int w  = tid >> 6;             // 0..7
    const int wm = w >> 1, wn = w & 1;
    const int rb = blockIdx.x & 63;
    const int cs = blockIdx.x >> 6;
    const int r0 = rb * 64 + wm * 16;    // wave pair-row base
    const int c0 = cs * 128;             // block pair-col base
    const int lc = l & 15;               // frag row/col within 16
    const int lk = l >> 4;               // k-group

    const s8v* hb8 = (const s8v*)hb;     // 16 x s8v per row of 128 bf16

#define STAGE(BUF, T) do {                                                        \
    _Pragma("unroll")                                                             \
    for (int i = 0; i < 2; i++) {                                                 \
        const int seg  = w * 2 + i;        /* 0..15 */                            \
        const int lrw  = seg * 4 + lk;     /* local row 0..63 */                  \
        const int grow = c0 + (T) * 32 + ((lrw < 32) ? lrw : (lrw - 32 + B_ROWS));\
        const int sc16 = lc ^ (lrw & 7);   /* source pre-swizzle */               \
        gload_lds16((const char*)hb + ((size_t)grow << 8) + (sc16 << 4),          \
                    (char*)&ldsB[BUF][seg * 4][0]);                               \
    }                                                                             \
} while (0)

    // prologue: stage B tile 0 (async); load per-thread S values; load A frags
    STAGE(0, 0);

    // s2r[r][t] = (col==row) ? 0 : 1 - S^2  for this thread's 4 rows x 4 t-cols
    float s2r[4][4];
    {
        const int grow0 = rb * 64 + wm * 16 + lk * 4;   // + r
        const int gcol0 = c0 + wn * 16 + lc;            // + t*32
        const float* gS = S + (size_t)grow0 * B_ROWS + gcol0;
        #pragma unroll
        for (int r = 0; r < 4; r++)
            #pragma unroll
            for (int t = 0; t < 4; t++) {
                float x = gS[(size_t)r * B_ROWS + t * 32];
                bool msk = (gcol0 + t * 32) == (grow0 + r);
                s2r[r][t] = msk ? 0.f : fmaf(-x, x, 1.f);
            }
    }

    s8v afr[2][4];
    #pragma unroll
    for (int fm = 0; fm < 2; fm++) {
        int ar = r0 + lc + fm * B_ROWS;
        #pragma unroll
        for (int kk = 0; kk < 4; kk++)
            afr[fm][kk] = hb8[ar * 16 + kk * 4 + lk];
    }

    // keep-alive pin (rule #17): forces the s2r load+mask chain to complete
    // HERE (latency overlaps STAGE(0) drain) and keeps values in registers
    // across the loop instead of letting the compiler sink the loads.
    #pragma unroll
    for (int r = 0; r < 4; r++)
        #pragma unroll
        for (int t = 0; t < 4; t++)
            asm volatile("" :: "v"(s2r[r][t]));

    __syncthreads();   // B tile 0 + afr ready

    float ssum[2][4];
    #pragma unroll
    for (int fm = 0; fm < 2; fm++)
        #pragma unroll
        for (int r = 0; r < 4; r++) ssum[fm][r] = 0.f;

    // loop-invariant ds_read addrs; +BUF*16384 / +8192 are immediate offsets
    const char* bp[4];
    {
        const char* bb = (const char*)ldsB + (wn * 16 + lc) * 256;
        #pragma unroll
        for (int kk = 0; kk < 4; kk++)
            bp[kk] = bb + (((kk * 4 + lk) ^ (lc & 7)) << 4);
    }

#define COMPUTE(BUF, T) do {                                                      \
    f4v acc[2][2];                                                                \
    _Pragma("unroll")                                                             \
    for (int fm = 0; fm < 2; fm++)                                                \
        _Pragma("unroll")                                                         \
        for (int fh = 0; fh < 2; fh++) acc[fm][fh] = f4v{0.f, 0.f, 0.f, 0.f};     \
    _Pragma("unroll")                                                             \
    for (int kk = 0; kk < 4; kk++) {                                              \
        s8v bf0 = *(const s8v*)(bp[kk] + ((BUF) * 16384));                        \
        s8v bf1 = *(const s8v*)(bp[kk] + ((BUF) * 16384 + 8192));                 \
        _Pragma("unroll")                                                         \
        for (int fm = 0; fm < 2; fm++) {                                          \
            acc[fm][0] = __builtin_amdgcn_mfma_f32_16x16x32_bf16(                 \
                afr[fm][kk], bf0, acc[fm][0], 0, 0, 0);                           \
            acc[fm][1] = __builtin_amdgcn_mfma_f32_16x16x32_bf16(                 \
                afr[fm][kk], bf1, acc[fm][1], 0, 0, 0);                           \
        }                                                                         \
    }                                                                             \
    _Pragma("unroll")                                                             \
    for (int r = 0; r < 4; r++) {                                                 \
        const float s2 = s2r[r][(T)];                                             \
        _Pragma("unroll")                                                         \
        for (int fm = 0; fm < 2; fm++) {                                          \
            float e0 = fast_exp2(fmaf(acc[fm][0][r], s2, -CSHIFT));               \
            float e1 = fast_exp2(fmaf(acc[fm][1][r], s2, -CSHIFT));               \
            ssum[fm][r] += e0 + e1;                                               \
        }                                                                         \
    }                                                                             \
} while (0)

    // 2-phase pipeline: stage next tile, compute current, barrier
    STAGE(1, 1); COMPUTE(0, 0); __syncthreads();
    STAGE(0, 2); COMPUTE(1, 1); __syncthreads();
    STAGE(1, 3); COMPUTE(0, 2); __syncthreads();
                 COMPUTE(1, 3);

#undef STAGE
#undef COMPUTE

    // pure-sum reduce over the 16 lanes holding each row, merge wn via LDS
    // merge scratch aliased into ldsB[0] (dead after COMPUTE(0,2) + barrier;
    // COMPUTE(1,3) reads only ldsB[1])
    float* sexb = (float*)&ldsB[0][0][0];   // [wn][fm][rho] = 256 floats
    #pragma unroll
    for (int fm = 0; fm < 2; fm++) {
        #pragma unroll
        for (int r = 0; r < 4; r++) {
            float ss = ssum[fm][r];
            #pragma unroll
            for (int off = 1; off < 16; off <<= 1)
                ss += __shfl_xor(ss, off, 64);
            if (lc == 0) {
                int rho = wm * 16 + lk * 4 + r;   // block-local pair-row 0..63
                sexb[wn * 128 + fm * 64 + rho] = ss;
            }
        }
    }
    __syncthreads();
    if (tid < 128) {
        int fm = tid >> 6, rho = tid & 63;
        float ss = sexb[fm * 64 + rho] + sexb[128 + fm * 64 + rho];
        int gr = rb * 64 + rho + fm * B_ROWS;
        ssplit[cs * NN + gr] = ss;
    }
}

// ---- kernel 3a: per-row split sum + lse, block partial sums (parallel) ----
__global__ __launch_bounds__(256)
void reduce_kernel(const float* __restrict__ ssplit, const float* __restrict__ pos2,
                   float* __restrict__ partial) {
    __shared__ float red[256];
    const int n = blockIdx.x * 256 + threadIdx.x;   // n < 8192
    float p = pos2[n & (B_ROWS - 1)];
    float Ssum = fast_exp2(p - CSHIFT);             // pos logit seeds the sum
    #pragma unroll
    for (int sp = 0; sp < NSPLIT; sp++)
        Ssum += ssplit[sp * NN + n];
    red[threadIdx.x] = (CSHIFT + log2f(Ssum)) - p;  // log2 units
    __syncthreads();
    for (int st = 128; st; st >>= 1) {
        if (threadIdx.x < st) red[threadIdx.x] += red[threadIdx.x + st];
        __syncthreads();
    }
    if (threadIdx.x == 0) partial[blockIdx.x] = red[0];
}

// ---- kernel 3b: deterministic final sum over 32 partials ----
__global__ void final_kernel(const float* __restrict__ partial, float* __restrict__ out) {
    if (threadIdx.x == 0) {
        float s = 0.f;
        #pragma unroll
        for (int i = 0; i < 32; i++) s += partial[i];
        out[0] = s * (LN2 / (float)NN);
    }
}

extern "C" void kernel_launch(void* const* d_in, const int* in_sizes, int n_in,
                              void* d_out, int out_size, void* d_ws, size_t ws_size,
                              hipStream_t stream) {
    (void)in_sizes; (void)n_in; (void)out_size; (void)ws_size;
    const float* hi = (const float*)d_in[0];
    const float* hj = (const float*)d_in[1];
    const float* S  = (const float*)d_in[2];

    char* ws = (char*)d_ws;
    __hip_bfloat16* hb = (__hip_bfloat16*)ws;                        // 2 MB
    float* pos2   = (float*)(ws + 2097152);                          // 16 KB
    float* ssplit = (float*)(ws + 2097152 + 16384);                  // 1 MB (32 splits)
    float* partial= (float*)(ws + 2097152 + 16384 + 1048576);        // 128 B

    hpos_kernel<<<1024, 256, 0, stream>>>(hi, hj, hb, pos2);
    main_kernel<<<2048, 512, 0, stream>>>(hb, S, ssplit);
    reduce_kernel<<<32, 256, 0, stream>>>(ssplit, pos2, partial);
    final_kernel<<<1, 64, 0, stream>>>(partial, (float*)d_out);
}

// Round 16
// 52.619 us; speedup vs baseline: 1.1861x; 1.1830x over previous
//
#include <hip/hip_runtime.h>
#include <hip/hip_bf16.h>

// Problem constants
#define B_ROWS 4096
#define NN     8192
#define DD     128
#define NSPLIT 64           // split s of row n = the "other" tile index
#define SPA    68           // s2m panel row stride in u16 (136 B, 8B-aligned stores)
#define CSHIFT 128.0f       // fixed logsumexp shift (log2 domain)

typedef __attribute__((ext_vector_type(8))) short s8v;   // 8 bf16 (4 VGPR)
typedef __attribute__((ext_vector_type(4))) float f4v;   // 4 f32
typedef __attribute__((ext_vector_type(2))) float f2v;
typedef __attribute__((ext_vector_type(4))) unsigned short u16x4;
typedef unsigned int u32;

static constexpr float SCALE_H = 1.6986436f;      // sqrt(2*log2(e)); folds /TEMP and log2e into the matmul
static constexpr float SCALE2  = 2.8853900818f;   // 2*log2(e)
static constexpr float LN2     = 0.6931471805599453f;

__device__ __forceinline__ float fast_exp2(float x) {
#if __has_builtin(__builtin_amdgcn_exp2f)
    return __builtin_amdgcn_exp2f(x);      // bare v_exp_f32
#else
    return exp2f(x);
#endif
}

// (1 - x^2) with mask folded in, rounded to bf16 bits
__device__ __forceinline__ unsigned short s2m_pack(float x, bool msk) {
    float s2 = msk ? 0.f : 1.f - x * x;    // s2m=0 => exp2(-CSHIFT) -> ~0
    union { __hip_bfloat16 h; unsigned short u; } cv;
    cv.h = __float2bfloat16(s2);
    return cv.u;
}

__device__ __forceinline__ float bf16f(unsigned short u) {
    return __uint_as_float(((u32)u) << 16);
}

typedef __attribute__((address_space(1))) const u32 gu32;
typedef __attribute__((address_space(3))) u32 lu32;
__device__ __forceinline__ void gload_lds16(const void* g, void* l) {
    // async global->LDS, 16B/lane; dest = lds base + lane*16 (wave-uniform base)
    __builtin_amdgcn_global_load_lds((gu32*)g, (lu32*)l, 16, 0, 0);
}

// ---- kernel 1: fused bf16-prep + pos dot ----
__global__ void hpos_kernel(const float* __restrict__ hi, const float* __restrict__ hj,
                            __hip_bfloat16* __restrict__ hb, float* __restrict__ pos2) {
    int w = threadIdx.x >> 6, l = threadIdx.x & 63;
    int row = blockIdx.x * 4 + w;
    f2v a = ((const f2v*)(hi + (size_t)row * DD))[l];
    f2v b = ((const f2v*)(hj + (size_t)row * DD))[l];
    float d = a[0] * b[0] + a[1] * b[1];
    #pragma unroll
    for (int off = 32; off; off >>= 1) d += __shfl_xor(d, off, 64);
    if (l == 0) pos2[row] = SCALE2 * d;
    union { ushort2 u2; __hip_bfloat16 h[2]; } ua, ub;
    ua.h[0] = __float2bfloat16(a[0] * SCALE_H);
    ua.h[1] = __float2bfloat16(a[1] * SCALE_H);
    ub.h[0] = __float2bfloat16(b[0] * SCALE_H);
    ub.h[1] = __float2bfloat16(b[1] * SCALE_H);
    ((ushort2*)(hb + (size_t)row * DD))[l] = ua.u2;
    ((ushort2*)(hb + (size_t)(row + B_ROWS) * DD))[l] = ub.u2;
}

// ---- kernel 2: symmetric-tile fused sim*S2 + fixed-shift sum-of-exp2 ----
// Grid 4096 = 64x64 tiles (i=row-tile, j=col-tile); blocks with i>j exit.
// Each live block (i<=j) computes the 64x64 pair-tile acc = sim once and runs
// TWO epilogues: row-view (S2[rr,cc] -> rows of tile i, split j) and col-view
// (S2[cc,rr] -> rows of tile j, split i; sim[y,x]==sim[x,y]). MFMA + B-tile
// staging + block count halve; exp2 total unchanged. Diag: row-view only,
// mask (rr==cc) folded into sA. 8 waves (wm 0..3, wn 0..1); per wave 16
// pair-rows x 32 pair-cols; single B tile (no t-loop), one compute barrier.
__global__ __launch_bounds__(512, 4)
void main_kernel(const __hip_bfloat16* __restrict__ hb, const float* __restrict__ S,
                 float* __restrict__ ssplit) {
    __shared__ short ldsB[128][128];           // 32 KB B tile (row-swizzled)
    __shared__ unsigned short sA[64][SPA];     // 8.5 KB row-view s2m (bf16)
    __shared__ unsigned short sB[64][SPA];     // 8.5 KB col-view s2m (bf16)
    __shared__ float mrg[768];                 // 3 KB merge scratch

    const int bid = blockIdx.x;
    const int i = bid >> 6, j = bid & 63;
    if (i > j) return;                         // upper triangle only
    const bool diag = (i == j);

    const int tid = threadIdx.x;
    const int l  = tid & 63;
    const int w  = tid >> 6;                   // 0..7
    const int wm = w >> 1, wn = w & 1;
    const int lc = l & 15;                     // frag row/col within 16
    const int lk = l >> 4;                     // k-group
    const int r64 = i * 64, c64 = j * 64;

    const s8v* hb8 = (const s8v*)hb;           // 16 x s8v per row of 128 bf16

    // ---- stage B tile: 128 hb-rows (64 pair-cols x 2 halves); 4 gloads/wave
    #pragma unroll
    for (int i2 = 0; i2 < 4; i2++) {
        const int rowb = w * 16 + i2 * 4;
        const int lrw  = rowb + lk;            // local row 0..127
        const int grow = c64 + ((lrw < 64) ? lrw : (lrw - 64 + B_ROWS));
        const int sc16 = lc ^ (lrw & 7);       // source pre-swizzle
        gload_lds16((const char*)hb + ((size_t)grow << 8) + (sc16 << 4),
                    (char*)&ldsB[rowb][0]);
    }

    // ---- stage S panels as bf16 s2m; sB = transposed block S[j-range, i-range]
    {
        const int rr = tid >> 3;               // 0..63
        const int c8 = (tid & 7) * 8;          // 0..56
        const float* gA = S + (size_t)(r64 + rr) * B_ROWS + c64 + c8;
        const float* gB = S + (size_t)(c64 + rr) * B_ROWS + r64 + c8;
        f4v a0 = ((const f4v*)gA)[0], a1 = ((const f4v*)gA)[1];
        f4v b0 = ((const f4v*)gB)[0], b1 = ((const f4v*)gB)[1];
        u16x4 pa0, pa1, pb0, pb1;
        #pragma unroll
        for (int e = 0; e < 4; e++) {
            pa0[e] = s2m_pack(a0[e], diag && (c8 + e     == rr));
            pa1[e] = s2m_pack(a1[e], diag && (c8 + 4 + e == rr));
            pb0[e] = s2m_pack(b0[e], false);   // col-view discarded on diag
            pb1[e] = s2m_pack(b1[e], false);
        }
        *(u16x4*)&sA[rr][c8]     = pa0;
        *(u16x4*)&sA[rr][c8 + 4] = pa1;
        *(u16x4*)&sB[rr][c8]     = pb0;
        *(u16x4*)&sB[rr][c8 + 4] = pb1;
    }

    // ---- A fragments: wave's 16 pair-rows x 2 halves
    s8v afr[2][4];
    #pragma unroll
    for (int fm = 0; fm < 2; fm++) {
        int ar = (r64 + wm * 16 + lc) + fm * B_ROWS;
        #pragma unroll
        for (int kk = 0; kk < 4; kk++)
            afr[fm][kk] = hb8[ar * 16 + kk * 4 + lk];
    }
    __syncthreads();   // B tile + panels + afr ready

    // ---- MFMA: 32 per wave (fm2 x fh2 x cg2 x kk4), acc[fm][fh][cg]
    const char* bp[4];
    {
        const char* bb = (const char*)ldsB + (wn * 32 + lc) * 256;
        #pragma unroll
        for (int kk = 0; kk < 4; kk++)
            bp[kk] = bb + (((kk * 4 + lk) ^ (lc & 7)) << 4);
    }
    f4v acc[2][2][2];
    #pragma unroll
    for (int fm = 0; fm < 2; fm++)
        #pragma unroll
        for (int fh = 0; fh < 2; fh++)
            #pragma unroll
            for (int cg = 0; cg < 2; cg++) acc[fm][fh][cg] = f4v{0.f, 0.f, 0.f, 0.f};
    #pragma unroll
    for (int kk = 0; kk < 4; kk++) {
        #pragma unroll
        for (int fh = 0; fh < 2; fh++)
            #pragma unroll
            for (int cg = 0; cg < 2; cg++) {
                s8v bf = *(const s8v*)(bp[kk] + fh * 16384 + cg * 4096);
                acc[0][fh][cg] = __builtin_amdgcn_mfma_f32_16x16x32_bf16(
                    afr[0][kk], bf, acc[0][fh][cg], 0, 0, 0);
                acc[1][fh][cg] = __builtin_amdgcn_mfma_f32_16x16x32_bf16(
                    afr[1][kk], bf, acc[1][fh][cg], 0, 0, 0);
            }
    }

    // ---- dual epilogue: row-view (sA[rr][cc]) + col-view (sB[cc][rr])
    float rsum[2][4], csum[2][2];
    #pragma unroll
    for (int fm = 0; fm < 2; fm++)
        #pragma unroll
        for (int r = 0; r < 4; r++) rsum[fm][r] = 0.f;
    csum[0][0] = csum[0][1] = csum[1][0] = csum[1][1] = 0.f;

    #pragma unroll
    for (int r = 0; r < 4; r++) {
        const int rr = wm * 16 + lk * 4 + r;
        #pragma unroll
        for (int cg = 0; cg < 2; cg++) {
            const int cc = wn * 32 + cg * 16 + lc;
            const float s2a = bf16f(sA[rr][cc]);
            const float s2b = bf16f(sB[cc][rr]);
            #pragma unroll
            for (int fm = 0; fm < 2; fm++)
                #pragma unroll
                for (int fh = 0; fh < 2; fh++) {
                    const float a = acc[fm][fh][cg][r];
                    rsum[fm][r]  += fast_exp2(fmaf(a, s2a, -CSHIFT));
                    csum[fh][cg] += fast_exp2(fmaf(a, s2b, -CSHIFT));
                }
        }
    }

    // ---- row reduce (over lc) -> mrg[0..255]; col reduce (over lk) -> mrg[256..767]
    #pragma unroll
    for (int fm = 0; fm < 2; fm++) {
        #pragma unroll
        for (int r = 0; r < 4; r++) {
            float ss = rsum[fm][r];
            #pragma unroll
            for (int off = 1; off < 16; off <<= 1) ss += __shfl_xor(ss, off, 64);
            if (lc == 0) mrg[wn * 128 + fm * 64 + (wm * 16 + lk * 4 + r)] = ss;
        }
    }
    #pragma unroll
    for (int fh = 0; fh < 2; fh++) {
        #pragma unroll
        for (int cg = 0; cg < 2; cg++) {
            float ss = csum[fh][cg];
            ss += __shfl_xor(ss, 16, 64);
            ss += __shfl_xor(ss, 32, 64);
            if (l < 16) mrg[256 + wm * 128 + fh * 64 + (wn * 32 + cg * 16 + lc)] = ss;
        }
    }
    __syncthreads();

    if (tid < 128) {                 // row-view -> split j, rows of tile i
        int fm = tid >> 6, rho = tid & 63;
        float v = mrg[fm * 64 + rho] + mrg[128 + fm * 64 + rho];
        ssplit[(size_t)j * NN + (r64 + rho + fm * B_ROWS)] = v;
    } else if (!diag && tid < 256) { // col-view -> split i, rows of tile j
        int t2 = tid - 128, fh = t2 >> 6, cc = t2 & 63;
        float v = mrg[256 +   0 + fh * 64 + cc] + mrg[256 + 128 + fh * 64 + cc]
                + mrg[256 + 256 + fh * 64 + cc] + mrg[256 + 384 + fh * 64 + cc];
        ssplit[(size_t)i * NN + (c64 + cc + fh * B_ROWS)] = v;
    }
}

// ---- kernel 3a: per-row split sum + lse, block partial sums (parallel) ----
__global__ __launch_bounds__(256)
void reduce_kernel(const float* __restrict__ ssplit, const float* __restrict__ pos2,
                   float* __restrict__ partial) {
    __shared__ float red[256];
    const int n = blockIdx.x * 256 + threadIdx.x;   // n < 8192
    float p = pos2[n & (B_ROWS - 1)];
    float Ssum = fast_exp2(p - CSHIFT);             // pos logit seeds the sum
    #pragma unroll 8
    for (int sp = 0; sp < NSPLIT; sp++)
        Ssum += ssplit[(size_t)sp * NN + n];
    red[threadIdx.x] = (CSHIFT + log2f(Ssum)) - p;  // log2 units
    __syncthreads();
    for (int st = 128; st; st >>= 1) {
        if (threadIdx.x < st) red[threadIdx.x] += red[threadIdx.x + st];
        __syncthreads();
    }
    if (threadIdx.x == 0) partial[blockIdx.x] = red[0];
}

// ---- kernel 3b: deterministic final sum over 32 partials ----
__global__ void final_kernel(const float* __restrict__ partial, float* __restrict__ out) {
    if (threadIdx.x == 0) {
        float s = 0.f;
        #pragma unroll
        for (int i = 0; i < 32; i++) s += partial[i];
        out[0] = s * (LN2 / (float)NN);
    }
}

extern "C" void kernel_launch(void* const* d_in, const int* in_sizes, int n_in,
                              void* d_out, int out_size, void* d_ws, size_t ws_size,
                              hipStream_t stream) {
    (void)in_sizes; (void)n_in; (void)out_size; (void)ws_size;
    const float* hi = (const float*)d_in[0];
    const float* hj = (const float*)d_in[1];
    const float* S  = (const float*)d_in[2];

    char* ws = (char*)d_ws;
    __hip_bfloat16* hb = (__hip_bfloat16*)ws;                        // 2 MB
    float* pos2   = (float*)(ws + 2097152);                          // 16 KB
    float* ssplit = (float*)(ws + 2097152 + 16384);                  // 2 MB (64 splits)
    float* partial= (float*)(ws + 2097152 + 16384 + 2097152);        // 128 B

    hpos_kernel<<<1024, 256, 0, stream>>>(hi, hj, hb, pos2);
    main_kernel<<<4096, 512, 0, stream>>>(hb, S, ssplit);
    reduce_kernel<<<32, 256, 0, stream>>>(ssplit, pos2, partial);
    final_kernel<<<1, 64, 0, stream>>>(partial, (float*)d_out);
}

// Round 17
// 46.286 us; speedup vs baseline: 1.3484x; 1.1368x over previous
//
#include <hip/hip_runtime.h>
#include <hip/hip_bf16.h>

// Problem constants
#define B_ROWS 4096
#define NN     8192
#define DD     128
#define NSPLIT 64           // split s of row n = the "other" tile index
#define NTRI   2080         // 64*65/2 upper-triangular tiles
#define SPA    68           // s2m panel row stride in u16 (136 B, 8B-aligned stores)
#define CSHIFT 128.0f       // fixed logsumexp shift (log2 domain)

typedef __attribute__((ext_vector_type(8))) short s8v;   // 8 bf16 (4 VGPR)
typedef __attribute__((ext_vector_type(4))) float f4v;   // 4 f32
typedef __attribute__((ext_vector_type(2))) float f2v;
typedef __attribute__((ext_vector_type(4))) unsigned short u16x4;
typedef unsigned int u32;

static constexpr float SCALE_H = 1.6986436f;      // sqrt(2*log2(e)); folds /TEMP and log2e into the matmul
static constexpr float SCALE2  = 2.8853900818f;   // 2*log2(e)
static constexpr float LN2     = 0.6931471805599453f;

__device__ __forceinline__ float fast_exp2(float x) {
#if __has_builtin(__builtin_amdgcn_exp2f)
    return __builtin_amdgcn_exp2f(x);      // bare v_exp_f32
#else
    return exp2f(x);
#endif
}

// (1 - x^2) with mask folded in, rounded to bf16 bits
__device__ __forceinline__ unsigned short s2m_pack(float x, bool msk) {
    float s2 = msk ? 0.f : 1.f - x * x;    // s2m=0 => exp2(-CSHIFT) -> ~0
    union { __hip_bfloat16 h; unsigned short u; } cv;
    cv.h = __float2bfloat16(s2);
    return cv.u;
}

__device__ __forceinline__ float bf16f(unsigned short u) {
    return __uint_as_float(((u32)u) << 16);
}

typedef __attribute__((address_space(1))) const u32 gu32;
typedef __attribute__((address_space(3))) u32 lu32;
__device__ __forceinline__ void gload_lds16(const void* g, void* l) {
    // async global->LDS, 16B/lane; dest = lds base + lane*16 (wave-uniform base)
    __builtin_amdgcn_global_load_lds((gu32*)g, (lu32*)l, 16, 0, 0);
}

// ---- kernel 1: fused bf16-prep + pos dot ----
__global__ void hpos_kernel(const float* __restrict__ hi, const float* __restrict__ hj,
                            __hip_bfloat16* __restrict__ hb, float* __restrict__ pos2) {
    int w = threadIdx.x >> 6, l = threadIdx.x & 63;
    int row = blockIdx.x * 4 + w;
    f2v a = ((const f2v*)(hi + (size_t)row * DD))[l];
    f2v b = ((const f2v*)(hj + (size_t)row * DD))[l];
    float d = a[0] * b[0] + a[1] * b[1];
    #pragma unroll
    for (int off = 32; off; off >>= 1) d += __shfl_xor(d, off, 64);
    if (l == 0) pos2[row] = SCALE2 * d;
    union { ushort2 u2; __hip_bfloat16 h[2]; } ua, ub;
    ua.h[0] = __float2bfloat16(a[0] * SCALE_H);
    ua.h[1] = __float2bfloat16(a[1] * SCALE_H);
    ub.h[0] = __float2bfloat16(b[0] * SCALE_H);
    ub.h[1] = __float2bfloat16(b[1] * SCALE_H);
    ((ushort2*)(hb + (size_t)row * DD))[l] = ua.u2;
    ((ushort2*)(hb + (size_t)(row + B_ROWS) * DD))[l] = ub.u2;
}

// ---- kernel 2: symmetric-tile fused sim*S2 + fixed-shift sum-of-exp2 ----
// R15 structure, exact-triangular launch: grid = 2080 live blocks; (i,j)
// decoded from the linear id (i<=j); XCD-bijective swizzle groups contiguous
// triangular ranges per XCD (hb-tile + S-row L2 locality). Dual epilogue:
// row-view -> split j rows of tile i; col-view -> split i rows of tile j.
__global__ __launch_bounds__(512, 4)
void main_kernel(const __hip_bfloat16* __restrict__ hb, const float* __restrict__ S,
                 float* __restrict__ ssplit) {
    __shared__ short ldsB[128][128];           // 32 KB B tile (row-swizzled)
    __shared__ unsigned short sA[64][SPA];     // 8.5 KB row-view s2m (bf16)
    __shared__ unsigned short sB[64][SPA];     // 8.5 KB col-view s2m (bf16)
    __shared__ float mrg[768];                 // 3 KB merge scratch

    // XCD-bijective swizzle (2080 % 8 == 0) + triangular decode (i <= j)
    const int orig = blockIdx.x;
    const int bid  = (orig & 7) * (NTRI / 8) + (orig >> 3);
    int j = (int)((sqrtf(8.0f * (float)bid + 1.0f) - 1.0f) * 0.5f);
    while (((j + 1) * (j + 2)) / 2 <= bid) ++j;   // fixup fp error (exact)
    while ((j * (j + 1)) / 2 > bid) --j;
    const int i = bid - (j * (j + 1)) / 2;
    const bool diag = (i == j);

    const int tid = threadIdx.x;
    const int l  = tid & 63;
    const int w  = tid >> 6;                   // 0..7
    const int wm = w >> 1, wn = w & 1;
    const int lc = l & 15;                     // frag row/col within 16
    const int lk = l >> 4;                     // k-group
    const int r64 = i * 64, c64 = j * 64;

    const s8v* hb8 = (const s8v*)hb;           // 16 x s8v per row of 128 bf16

    // ---- stage B tile: 128 hb-rows (64 pair-cols x 2 halves); 4 gloads/wave
    #pragma unroll
    for (int i2 = 0; i2 < 4; i2++) {
        const int rowb = w * 16 + i2 * 4;
        const int lrw  = rowb + lk;            // local row 0..127
        const int grow = c64 + ((lrw < 64) ? lrw : (lrw - 64 + B_ROWS));
        const int sc16 = lc ^ (lrw & 7);       // source pre-swizzle
        gload_lds16((const char*)hb + ((size_t)grow << 8) + (sc16 << 4),
                    (char*)&ldsB[rowb][0]);
    }

    // ---- stage S panels as bf16 s2m; sB = transposed block S[j-range, i-range]
    {
        const int rr = tid >> 3;               // 0..63
        const int c8 = (tid & 7) * 8;          // 0..56
        const float* gA = S + (size_t)(r64 + rr) * B_ROWS + c64 + c8;
        const float* gB = S + (size_t)(c64 + rr) * B_ROWS + r64 + c8;
        f4v a0 = ((const f4v*)gA)[0], a1 = ((const f4v*)gA)[1];
        f4v b0 = ((const f4v*)gB)[0], b1 = ((const f4v*)gB)[1];
        u16x4 pa0, pa1, pb0, pb1;
        #pragma unroll
        for (int e = 0; e < 4; e++) {
            pa0[e] = s2m_pack(a0[e], diag && (c8 + e     == rr));
            pa1[e] = s2m_pack(a1[e], diag && (c8 + 4 + e == rr));
            pb0[e] = s2m_pack(b0[e], false);   // col-view discarded on diag
            pb1[e] = s2m_pack(b1[e], false);
        }
        *(u16x4*)&sA[rr][c8]     = pa0;
        *(u16x4*)&sA[rr][c8 + 4] = pa1;
        *(u16x4*)&sB[rr][c8]     = pb0;
        *(u16x4*)&sB[rr][c8 + 4] = pb1;
    }

    // ---- A fragments: wave's 16 pair-rows x 2 halves
    s8v afr[2][4];
    #pragma unroll
    for (int fm = 0; fm < 2; fm++) {
        int ar = (r64 + wm * 16 + lc) + fm * B_ROWS;
        #pragma unroll
        for (int kk = 0; kk < 4; kk++)
            afr[fm][kk] = hb8[ar * 16 + kk * 4 + lk];
    }
    __syncthreads();   // B tile + panels + afr ready

    // ---- MFMA: 32 per wave (fm2 x fh2 x cg2 x kk4), acc[fm][fh][cg]
    const char* bp[4];
    {
        const char* bb = (const char*)ldsB + (wn * 32 + lc) * 256;
        #pragma unroll
        for (int kk = 0; kk < 4; kk++)
            bp[kk] = bb + (((kk * 4 + lk) ^ (lc & 7)) << 4);
    }
    f4v acc[2][2][2];
    #pragma unroll
    for (int fm = 0; fm < 2; fm++)
        #pragma unroll
        for (int fh = 0; fh < 2; fh++)
            #pragma unroll
            for (int cg = 0; cg < 2; cg++) acc[fm][fh][cg] = f4v{0.f, 0.f, 0.f, 0.f};
    #pragma unroll
    for (int kk = 0; kk < 4; kk++) {
        #pragma unroll
        for (int fh = 0; fh < 2; fh++)
            #pragma unroll
            for (int cg = 0; cg < 2; cg++) {
                s8v bf = *(const s8v*)(bp[kk] + fh * 16384 + cg * 4096);
                acc[0][fh][cg] = __builtin_amdgcn_mfma_f32_16x16x32_bf16(
                    afr[0][kk], bf, acc[0][fh][cg], 0, 0, 0);
                acc[1][fh][cg] = __builtin_amdgcn_mfma_f32_16x16x32_bf16(
                    afr[1][kk], bf, acc[1][fh][cg], 0, 0, 0);
            }
    }

    // ---- dual epilogue: row-view (sA[rr][cc]) + col-view (sB[cc][rr])
    float rsum[2][4], csum[2][2];
    #pragma unroll
    for (int fm = 0; fm < 2; fm++)
        #pragma unroll
        for (int r = 0; r < 4; r++) rsum[fm][r] = 0.f;
    csum[0][0] = csum[0][1] = csum[1][0] = csum[1][1] = 0.f;

    #pragma unroll
    for (int r = 0; r < 4; r++) {
        const int rr = wm * 16 + lk * 4 + r;
        #pragma unroll
        for (int cg = 0; cg < 2; cg++) {
            const int cc = wn * 32 + cg * 16 + lc;
            const float s2a = bf16f(sA[rr][cc]);
            const float s2b = bf16f(sB[cc][rr]);
            #pragma unroll
            for (int fm = 0; fm < 2; fm++)
                #pragma unroll
                for (int fh = 0; fh < 2; fh++) {
                    const float a = acc[fm][fh][cg][r];
                    rsum[fm][r]  += fast_exp2(fmaf(a, s2a, -CSHIFT));
                    csum[fh][cg] += fast_exp2(fmaf(a, s2b, -CSHIFT));
                }
        }
    }

    // ---- row reduce (over lc) -> mrg[0..255]; col reduce (over lk) -> mrg[256..767]
    #pragma unroll
    for (int fm = 0; fm < 2; fm++) {
        #pragma unroll
        for (int r = 0; r < 4; r++) {
            float ss = rsum[fm][r];
            #pragma unroll
            for (int off = 1; off < 16; off <<= 1) ss += __shfl_xor(ss, off, 64);
            if (lc == 0) mrg[wn * 128 + fm * 64 + (wm * 16 + lk * 4 + r)] = ss;
        }
    }
    #pragma unroll
    for (int fh = 0; fh < 2; fh++) {
        #pragma unroll
        for (int cg = 0; cg < 2; cg++) {
            float ss = csum[fh][cg];
            ss += __shfl_xor(ss, 16, 64);
            ss += __shfl_xor(ss, 32, 64);
            if (l < 16) mrg[256 + wm * 128 + fh * 64 + (wn * 32 + cg * 16 + lc)] = ss;
        }
    }
    __syncthreads();

    if (tid < 128) {                 // row-view -> split j, rows of tile i
        int fm = tid >> 6, rho = tid & 63;
        float v = mrg[fm * 64 + rho] + mrg[128 + fm * 64 + rho];
        ssplit[(size_t)j * NN + (r64 + rho + fm * B_ROWS)] = v;
    } else if (!diag && tid < 256) { // col-view -> split i, rows of tile j
        int t2 = tid - 128, fh = t2 >> 6, cc = t2 & 63;
        float v = mrg[256 +   0 + fh * 64 + cc] + mrg[256 + 128 + fh * 64 + cc]
                + mrg[256 + 256 + fh * 64 + cc] + mrg[256 + 384 + fh * 64 + cc];
        ssplit[(size_t)i * NN + (c64 + cc + fh * B_ROWS)] = v;
    }
}

// ---- kernel 3a: per-row split sum + lse, block partial sums (parallel) ----
__global__ __launch_bounds__(256)
void reduce_kernel(const float* __restrict__ ssplit, const float* __restrict__ pos2,
                   float* __restrict__ partial) {
    __shared__ float red[256];
    const int n = blockIdx.x * 256 + threadIdx.x;   // n < 8192
    float p = pos2[n & (B_ROWS - 1)];
    float Ssum = fast_exp2(p - CSHIFT);             // pos logit seeds the sum
    #pragma unroll 8
    for (int sp = 0; sp < NSPLIT; sp++)
        Ssum += ssplit[(size_t)sp * NN + n];
    red[threadIdx.x] = (CSHIFT + log2f(Ssum)) - p;  // log2 units
    __syncthreads();
    for (int st = 128; st; st >>= 1) {
        if (threadIdx.x < st) red[threadIdx.x] += red[threadIdx.x + st];
        __syncthreads();
    }
    if (threadIdx.x == 0) partial[blockIdx.x] = red[0];
}

// ---- kernel 3b: deterministic final sum over 32 partials ----
__global__ void final_kernel(const float* __restrict__ partial, float* __restrict__ out) {
    if (threadIdx.x == 0) {
        float s = 0.f;
        #pragma unroll
        for (int i = 0; i < 32; i++) s += partial[i];
        out[0] = s * (LN2 / (float)NN);
    }
}

extern "C" void kernel_launch(void* const* d_in, const int* in_sizes, int n_in,
                              void* d_out, int out_size, void* d_ws, size_t ws_size,
                              hipStream_t stream) {
    (void)in_sizes; (void)n_in; (void)out_size; (void)ws_size;
    const float* hi = (const float*)d_in[0];
    const float* hj = (const float*)d_in[1];
    const float* S  = (const float*)d_in[2];

    char* ws = (char*)d_ws;
    __hip_bfloat16* hb = (__hip_bfloat16*)ws;                        // 2 MB
    float* pos2   = (float*)(ws + 2097152);                          // 16 KB
    float* ssplit = (float*)(ws + 2097152 + 16384);                  // 2 MB (64 splits)
    float* partial= (float*)(ws + 2097152 + 16384 + 2097152);        // 128 B

    hpos_kernel<<<1024, 256, 0, stream>>>(hi, hj, hb, pos2);
    main_kernel<<<NTRI, 512, 0, stream>>>(hb, S, ssplit);
    reduce_kernel<<<32, 256, 0, stream>>>(ssplit, pos2, partial);
    final_kernel<<<1, 64, 0, stream>>>(partial, (float*)d_out);
}